// Round 2
// baseline (764.936 us; speedup 1.0000x reference)
//
#include <hip/hip_runtime.h>
#include <cstdint>

// Shapes (fixed): B=4, L=512, H=8, Dk=Dv=64, dm=512
typedef __attribute__((ext_vector_type(8))) short short8;   // 8 bf16 (4 VGPRs)
typedef __attribute__((ext_vector_type(4))) float f32x4;    // MFMA accumulator

__device__ __forceinline__ unsigned short f2bf(float f){
  union { float f; unsigned u; } v; v.f = f;
  return (unsigned short)((v.u + 0x7fffu + ((v.u >> 16) & 1u)) >> 16);
}
__device__ __forceinline__ short8 ld8(const unsigned short* p){ return *(const short8*)p; }
__device__ __forceinline__ f32x4 mfma16(short8 a, short8 b, f32x4 c){
  return __builtin_amdgcn_mfma_f32_16x16x32_bf16(a, b, c, 0, 0, 0);
}
__device__ __forceinline__ short8 cvt8(float4 a, float4 b){
  short8 r;
  r[0]=f2bf(a.x); r[1]=f2bf(a.y); r[2]=f2bf(a.z); r[3]=f2bf(a.w);
  r[4]=f2bf(b.x); r[5]=f2bf(b.y); r[6]=f2bf(b.z); r[7]=f2bf(b.w);
  return r;
}
__device__ __forceinline__ float gelu_tanh(float x){
  float u = 0.7978845608028654f * (x + 0.044715f * x * x * x);
  return 0.5f * x * (1.f + tanhf(u));
}

// ---- prep: blocks <3072: q,k,v f32->bf16 [3][2048][512]; rest: LDS-tiled
//      transpose+convert of 6 weights [512][512] f32 -> [N][K] bf16 ----
__global__ __launch_bounds__(256) void k_prep(const float* __restrict__ q,
    const float* __restrict__ k, const float* __restrict__ v,
    const float* __restrict__ w0, const float* __restrict__ w1,
    const float* __restrict__ w2, const float* __restrict__ w3,
    const float* __restrict__ w4, const float* __restrict__ w5,
    unsigned short* __restrict__ xin, unsigned short* __restrict__ Wt){
  __shared__ unsigned short tl[64 * 72];
  int bid = blockIdx.x, t = threadIdx.x;
  if (bid < 3072){
    int i = bid * 256 + t;                     // float4 units
    int w = i >> 18, r = i & 262143;
    const float* src = (w == 0) ? q : (w == 1) ? k : v;
    float4 f = *(const float4*)(src + (size_t)r * 4);
    unsigned lo = (unsigned)f2bf(f.x) | ((unsigned)f2bf(f.y) << 16);
    unsigned hi = (unsigned)f2bf(f.z) | ((unsigned)f2bf(f.w) << 16);
    uint2 o; o.x = lo; o.y = hi;
    *(uint2*)(xin + (size_t)w * 1048576 + (size_t)r * 4) = o;
  } else {
    int b2 = bid - 3072;
    int mat = b2 >> 6, tile = b2 & 63;
    int kt = tile >> 3, nt = tile & 7;
    const float* src = (mat == 0) ? w0 : (mat == 1) ? w1 : (mat == 2) ? w2 :
                       (mat == 3) ? w3 : (mat == 4) ? w4 : w5;
    int c = t & 63, r0 = t >> 6;
    for (int j = 0; j < 16; j++){
      int kl = r0 * 16 + j;
      tl[c * 72 + kl] = f2bf(src[(size_t)(kt * 64 + kl) * 512 + nt * 64 + c]);
    }
    __syncthreads();
    unsigned short* dst = Wt + (size_t)mat * 262144;
    for (int j = 0; j < 16; j++){
      int nl = r0 * 16 + j;
      dst[(size_t)(nt * 64 + nl) * 512 + kt * 64 + c] = tl[nl * 72 + c];
    }
  }
}

// ---- projections (3 in one launch): [2048,512]@W -> permuted bf16
// mode 0: qs (1/8) -> [B,H,L,D]; 1: kh -> [B,H,L,D]; 2: vhT -> [B,H,D,L] ----
__global__ __launch_bounds__(256) void k_proj(const unsigned short* __restrict__ xin,
    const unsigned short* __restrict__ Wt, unsigned short* __restrict__ qsb,
    unsigned short* __restrict__ khb, unsigned short* __restrict__ vhT){
  int mode = blockIdx.x >> 10;
  int wid = (blockIdx.x & 1023) * 4 + (threadIdx.x >> 6);
  int lane = threadIdx.x & 63;
  int tm = wid >> 5, tn = wid & 31;
  int r = lane & 15, q = lane >> 4;
  const unsigned short* A  = xin + (size_t)mode * 1048576 + (size_t)(tm * 16 + r) * 512 + q * 8;
  const unsigned short* Bp = Wt  + (size_t)mode * 262144  + (size_t)(tn * 16 + r) * 512 + q * 8;
  f32x4 acc = {0.f, 0.f, 0.f, 0.f};
  for (int k = 0; k < 512; k += 32) acc = mfma16(ld8(A + k), ld8(Bp + k), acc);
  int col = tn * 16 + r;
  int h = col >> 6, d = col & 63;
  float sc = (mode == 0) ? 0.125f : 1.0f;
  unsigned short* dst = (mode == 0) ? qsb : (mode == 1) ? khb : vhT;
  for (int i = 0; i < 4; i++){
    int row = tm * 16 + q * 4 + i;
    int b = row >> 9, l = row & 511;
    size_t idx = (mode == 2) ? ((size_t)((b * 8 + h) * 64 + d) * 512 + l)
                             : ((size_t)((b * 8 + h) * 512 + l) * 64 + d);
    dst[idx] = f2bf(acc[i] * sc);
  }
}

// ---- content scores: per (b,h): qs[512,64] @ kh[512,64]^T -> attnF f32 ----
__global__ __launch_bounds__(256) void k_scores(const unsigned short* __restrict__ qs,
    const unsigned short* __restrict__ kh, float* __restrict__ attnF){
  int wid = blockIdx.x * 4 + (threadIdx.x >> 6);
  int lane = threadIdx.x & 63;
  int bh = wid >> 10, tile = wid & 1023;
  int tm = tile >> 5, tn = tile & 31;
  int r = lane & 15, q = lane >> 4;
  const unsigned short* A  = qs + (size_t)bh * 32768 + (size_t)(tm * 16 + r) * 64 + q * 8;
  const unsigned short* Bp = kh + (size_t)bh * 32768 + (size_t)(tn * 16 + r) * 64 + q * 8;
  f32x4 acc = {0.f, 0.f, 0.f, 0.f};
  acc = mfma16(ld8(A),      ld8(Bp),      acc);
  acc = mfma16(ld8(A + 32), ld8(Bp + 32), acc);
  float* C = attnF + (size_t)bh * 262144;
  for (int i = 0; i < 4; i++)
    C[(size_t)(tm * 16 + q * 4 + i) * 512 + tn * 16 + r] = acc[i];
}

// ---- fused attention per (b,l): rel scores (direct-load vak B-frags) +
//      mask + softmax + rel-PV (direct-load vav B-frags) ----
__global__ __launch_bounds__(256) void k_attn(const unsigned short* __restrict__ qsb,
    const float* __restrict__ vak, const float* __restrict__ vav,
    const int* __restrict__ adj, float* __restrict__ attnF,
    unsigned short* __restrict__ attnb, float* __restrict__ orel){
  int bid = blockIdx.x;
  int b = bid >> 9, l = bid & 511;
  int t = threadIdx.x, lane = t & 63, w = t >> 6;
  int r = lane & 15, q = lane >> 4;
  __shared__ __align__(16) unsigned short qsA[16 * 72];
  __shared__ float sc[8 * 512];
  __shared__ int adjs[512];
  __shared__ __align__(16) unsigned short pb[16 * 520];
  // qs rows (heads) 0..7; rows 8..15 zero
  for (int i = 0; i < 4; i++){
    int m = w * 4 + i;
    unsigned short vle = 0;
    if (m < 8) vle = qsb[((size_t)((b * 8 + m) * 512 + l)) * 64 + lane];
    qsA[m * 72 + lane] = vle;
  }
  for (int j = 0; j < 16; j++){
    int e = t + j * 256;
    int h = e >> 9, m = e & 511;
    sc[e] = attnF[((size_t)(b * 8 + h) * 512 + l) * 512 + m];
  }
  adjs[t]       = adj[(size_t)bid * 512 + t];
  adjs[t + 256] = adj[(size_t)bid * 512 + t + 256];
  __syncthreads();
  // rel scores: wave w owns m-tiles w*8..w*8+7 (disjoint sc columns)
  short8 a0 = ld8(qsA + r * 72 + q * 8);
  short8 a1 = ld8(qsA + r * 72 + 32 + q * 8);
  const float* vrow = vak + (size_t)bid * 32768;
  for (int tt = 0; tt < 8; tt++){
    int nt = w * 8 + tt;
    const float* bp = vrow + (size_t)(nt * 16 + r) * 64 + q * 8;
    float4 f0 = *(const float4*)(bp);
    float4 f1 = *(const float4*)(bp + 4);
    float4 f2 = *(const float4*)(bp + 32);
    float4 f3 = *(const float4*)(bp + 36);
    f32x4 acc = {0.f, 0.f, 0.f, 0.f};
    acc = mfma16(a0, cvt8(f0, f1), acc);
    acc = mfma16(a1, cvt8(f2, f3), acc);
    if (q < 2)
      for (int i = 0; i < 4; i++) sc[(q * 4 + i) * 512 + nt * 16 + r] += acc[i];
  }
  __syncthreads();
  // mask + softmax: wave w -> heads 2w, 2w+1
  for (int hh = 0; hh < 2; hh++){
    int h = w * 2 + hh;
    float vv[8]; float mx = -3.0e38f;
    for (int i = 0; i < 8; i++){
      int m = lane + i * 64;
      float s = sc[h * 512 + m];
      if (adjs[m] == 0) s = -10000.0f;
      vv[i] = s; mx = fmaxf(mx, s);
    }
    for (int off = 32; off; off >>= 1) mx = fmaxf(mx, __shfl_xor(mx, off, 64));
    float sum = 0.f;
    for (int i = 0; i < 8; i++){ vv[i] = __expf(vv[i] - mx); sum += vv[i]; }
    for (int off = 32; off; off >>= 1) sum += __shfl_xor(sum, off, 64);
    float inv = 1.f / sum;
    size_t base = ((size_t)(b * 8 + h) * 512 + l) * 512;
    for (int i = 0; i < 8; i++){
      int m = lane + i * 64;
      float p = vv[i] * inv;
      attnF[base + m] = p;
      unsigned short pbf = f2bf(p);
      attnb[base + m] = pbf;
      pb[h * 520 + m] = pbf;       // A-operand layout for PV (rows 8..15 garbage, unused)
    }
  }
  __syncthreads();
  // rel-PV: wave w owns d-tile w; B-frags loaded straight from vav
  const float* vvrow = vav + (size_t)bid * 32768;
  int dcol = w * 16 + r;
  f32x4 acc = {0.f, 0.f, 0.f, 0.f};
  for (int kb = 0; kb < 16; kb++){
    int m0 = kb * 32 + q * 8;
    short8 bf;
    for (int j = 0; j < 8; j++) bf[j] = f2bf(vvrow[(size_t)(m0 + j) * 64 + dcol]);
    short8 af = ld8(pb + r * 520 + kb * 32 + q * 8);
    acc = mfma16(af, bf, acc);
  }
  if (q < 2)
    for (int i = 0; i < 4; i++)
      orel[(size_t)bid * 512 + (q * 4 + i) * 64 + dcol] = acc[i];
}

// ---- content PV: per (b,h): attn[512,512] @ vh[512,64] -> qc f32 [B,L,dm] ----
__global__ __launch_bounds__(256) void k_outc(const unsigned short* __restrict__ attn_bf,
    const unsigned short* __restrict__ vhT, float* __restrict__ qc){
  int wid = blockIdx.x * 4 + (threadIdx.x >> 6);
  int lane = threadIdx.x & 63;
  int bh = wid >> 7, tile = wid & 127;
  int tm = tile >> 2, tn = tile & 3;
  int r = lane & 15, q = lane >> 4;
  const unsigned short* A  = attn_bf + (size_t)bh * 262144 + (size_t)(tm * 16 + r) * 512 + q * 8;
  const unsigned short* Bp = vhT + (size_t)bh * 32768 + (size_t)(tn * 16 + r) * 512 + q * 8;
  f32x4 acc = {0.f, 0.f, 0.f, 0.f};
  for (int k = 0; k < 512; k += 32) acc = mfma16(ld8(A + k), ld8(Bp + k), acc);
  int b = bh >> 3, h = bh & 7;
  int d = tn * 16 + r;
  for (int i = 0; i < 4; i++){
    int lrow = tm * 16 + q * 4 + i;
    qc[(size_t)(b * 512 + lrow) * 512 + h * 64 + d] = acc[i];
  }
}

// ---- finalize qc: add rel part, bf16 cast, node weight + inv denom ----
__global__ __launch_bounds__(256) void k_fin(const float* __restrict__ qc,
    const float* __restrict__ orel, const int* __restrict__ adj,
    const float* __restrict__ wnw, unsigned short* __restrict__ qcb,
    float* __restrict__ nw, float* __restrict__ invd){
  int bid = blockIdx.x, t = threadIdx.x, lane = t & 63, w = t >> 6;
  __shared__ float redf[4];
  __shared__ int redi[4];
  float part = 0.f; int asum = 0;
  for (int j = 0; j < 2; j++){
    int e = t + j * 256;
    float val = qc[(size_t)bid * 512 + e] + orel[(size_t)bid * 512 + e];
    qcb[(size_t)bid * 512 + e] = f2bf(val);
    part += val * wnw[e];
    asum += adj[(size_t)bid * 512 + e];
  }
  for (int off = 32; off; off >>= 1){
    part += __shfl_xor(part, off, 64);
    asum += __shfl_xor(asum, off, 64);
  }
  if (lane == 0){ redf[w] = part; redi[w] = asum; }
  __syncthreads();
  if (t == 0){
    float tot = redf[0] + redf[1] + redf[2] + redf[3];
    int at = redi[0] + redi[1] + redi[2] + redi[3];
    nw[bid] = 1.f / (1.f + __expf(-tot));
    invd[bid] = 1.f / ((at >= 1) ? (float)at : 1.f);
  }
}

// ---- GNN GEMMs (2 in one launch): mode0 self_info f32; mode1 ddT bf16 ----
__global__ __launch_bounds__(256) void k_gnn(const unsigned short* __restrict__ qcb,
    const unsigned short* __restrict__ Wt, float* __restrict__ selfi,
    unsigned short* __restrict__ ddT){
  int mode = blockIdx.x >> 10;
  int wid = (blockIdx.x & 1023) * 4 + (threadIdx.x >> 6);
  int lane = threadIdx.x & 63;
  int tm = wid >> 5, tn = wid & 31;
  int r = lane & 15, q = lane >> 4;
  const unsigned short* A  = qcb + (size_t)(tm * 16 + r) * 512 + q * 8;
  const unsigned short* Bp = Wt + (size_t)(3 + mode) * 262144 + (size_t)(tn * 16 + r) * 512 + q * 8;
  f32x4 acc = {0.f, 0.f, 0.f, 0.f};
  for (int k = 0; k < 512; k += 32) acc = mfma16(ld8(A + k), ld8(Bp + k), acc);
  int col = tn * 16 + r;
  for (int i = 0; i < 4; i++){
    int row = tm * 16 + q * 4 + i;
    if (mode == 0) selfi[(size_t)row * 512 + col] = acc[i];
    else {
      int b = row >> 9, m = row & 511;
      ddT[((size_t)(b * 512 + col)) * 512 + m] = f2bf(acc[i]);  // [B][n][m]
    }
  }
}

// ---- agg GEMM per b: (ddw built on the fly from adj,nw,invd) @ dd_info + self ----
__global__ __launch_bounds__(256) void k_agg(const int* __restrict__ adj,
    const float* __restrict__ nw, const float* __restrict__ invd,
    const unsigned short* __restrict__ ddT, const float* __restrict__ selfi,
    unsigned short* __restrict__ xbf){
  int wid = blockIdx.x * 4 + (threadIdx.x >> 6);
  int lane = threadIdx.x & 63;
  int b = wid >> 10, tile = wid & 1023;
  int tm = tile >> 5, tn = tile & 31;
  int r = lane & 15, q = lane >> 4;
  int lrow = tm * 16 + r;
  float idv = invd[b * 512 + lrow];
  const int* arow = adj + ((size_t)b * 512 + lrow) * 512;
  const float* nwb = nw + b * 512;
  const unsigned short* Bp = ddT + (size_t)b * 262144 + (size_t)(tn * 16 + r) * 512 + q * 8;
  f32x4 acc = {0.f, 0.f, 0.f, 0.f};
  for (int kk = 0; kk < 512; kk += 32){
    int k0 = kk + q * 8;
    short8 af;
    for (int j = 0; j < 8; j++){
      float vv = arow[k0 + j] ? nwb[k0 + j] * idv : 0.f;
      af[j] = f2bf(vv);
    }
    acc = mfma16(af, ld8(Bp + kk), acc);
  }
  int col = tn * 16 + r;
  for (int i = 0; i < 4; i++){
    int row = b * 512 + tm * 16 + q * 4 + i;
    float x = acc[i] + selfi[(size_t)row * 512 + col];
    xbf[(size_t)row * 512 + col] = f2bf(x);
  }
}

// ---- final: xbf@Wfc -> gelu -> + residual -> qo f32 ----
__global__ __launch_bounds__(256) void k_fc(const unsigned short* __restrict__ xbf,
    const unsigned short* __restrict__ Wt, const float* __restrict__ qin,
    float* __restrict__ qo){
  int wid = blockIdx.x * 4 + (threadIdx.x >> 6);
  int lane = threadIdx.x & 63;
  int tm = wid >> 5, tn = wid & 31;
  int r = lane & 15, q = lane >> 4;
  const unsigned short* A  = xbf + (size_t)(tm * 16 + r) * 512 + q * 8;
  const unsigned short* Bp = Wt + (size_t)5 * 262144 + (size_t)(tn * 16 + r) * 512 + q * 8;
  f32x4 acc = {0.f, 0.f, 0.f, 0.f};
  for (int k = 0; k < 512; k += 32) acc = mfma16(ld8(A + k), ld8(Bp + k), acc);
  int col = tn * 16 + r;
  for (int i = 0; i < 4; i++){
    int row = tm * 16 + q * 4 + i;
    qo[(size_t)row * 512 + col] = qin[(size_t)row * 512 + col] + gelu_tanh(acc[i]);
  }
}

extern "C" void kernel_launch(void* const* d_in, const int* in_sizes, int n_in,
                              void* d_out, int out_size, void* d_ws, size_t ws_size,
                              hipStream_t stream){
  const float* q    = (const float*)d_in[0];
  const float* k    = (const float*)d_in[1];
  const float* v    = (const float*)d_in[2];
  const float* vak  = (const float*)d_in[3];
  const float* vav  = (const float*)d_in[4];
  const int*   adjk = (const int*)d_in[5];
  const float* wqs  = (const float*)d_in[7];
  const float* wks  = (const float*)d_in[8];
  const float* wvs  = (const float*)d_in[9];
  const float* wfc  = (const float*)d_in[10];
  const float* wnw  = (const float*)d_in[11];
  const float* wself= (const float*)d_in[12];
  const float* wdd  = (const float*)d_in[13];

  float* qo    = (float*)d_out;               // [4,512,512]
  float* attnF = qo + 1048576;                // [4,8,512,512]

  char* p = (char*)d_ws;
  unsigned short* xin   = (unsigned short*)p; p += 6291456;   // q,k,v bf16
  unsigned short* Wt    = (unsigned short*)p; p += 3145728;   // 6 W^T bf16
  unsigned short* qsb   = (unsigned short*)p; p += 2097152;   // [B,H,L,D]
  unsigned short* khb   = (unsigned short*)p; p += 2097152;   // [B,H,L,D]
  unsigned short* vhT   = (unsigned short*)p; p += 2097152;   // [B,H,D,L]
  unsigned short* attnb = (unsigned short*)p; p += 16777216;  // [B,H,L,L] bf16
  float*          qc    = (float*)p;          p += 4194304;   // [B,L,dm] content PV
  float*          orel  = (float*)p;          p += 4194304;   // [B,L,dm] rel PV
  unsigned short* qcb   = (unsigned short*)p; p += 2097152;
  float*          nw    = (float*)p;          p += 8192;
  float*          invd  = (float*)p;          p += 8192;
  float*          selfi = (float*)p;          p += 4194304;
  unsigned short* ddT   = (unsigned short*)p; p += 2097152;
  unsigned short* xbf   = (unsigned short*)p; p += 2097152;

  k_prep<<<3456, 256, 0, stream>>>(q, k, v, wqs, wks, wvs, wself, wdd, wfc, xin, Wt);
  k_proj<<<3072, 256, 0, stream>>>(xin, Wt, qsb, khb, vhT);
  k_scores<<<8192, 256, 0, stream>>>(qsb, khb, attnF);
  k_attn<<<2048, 256, 0, stream>>>(qsb, vak, vav, adjk, attnF, attnb, orel);
  k_outc<<<1024, 256, 0, stream>>>(attnb, vhT, qc);
  k_fin<<<2048, 256, 0, stream>>>(qc, orel, adjk, wnw, qcb, nw, invd);
  k_gnn<<<2048, 256, 0, stream>>>(qcb, Wt, selfi, ddT);
  k_agg<<<1024, 256, 0, stream>>>(adjk, nw, invd, ddT, selfi, xbf);
  k_fc<<<1024, 256, 0, stream>>>(xbf, Wt, q, qo);
}